// Round 11
// baseline (406.737 us; speedup 1.0000x reference)
//
#include <hip/hip_runtime.h>
#include <hip/hip_bf16.h>

#define BB 64
#define SS 4096
#define HH 256
#define AA 128
#define MT 128      // M tile per block (4 waves x 32 rows)
#define WST 264     // LDS row stride in f16 for Wt (256 + 8 pad, 16B-aligned rows)

typedef __fp16 fp16v2 __attribute__((ext_vector_type(2)));   // cvt_pkrtz result type
typedef _Float16 half8v __attribute__((ext_vector_type(8)));
typedef float floatx16 __attribute__((ext_vector_type(16)));

__device__ __forceinline__ float fast_tanh(float x) {
    float xc = fminf(fmaxf(x, -9.0f), 9.0f);
    float e = __expf(2.0f * xc);
    return 1.0f - __fdividef(2.0f, e + 1.0f);
}

// ---------------------------------------------------------------------------
// K0: W1 [H=256][A=128] fp32  ->  Wt [A=128][H=256] f16 (transposed) in d_ws
// ---------------------------------------------------------------------------
__global__ void convert_w1(const float* __restrict__ W1, _Float16* __restrict__ Wt) {
    int n = blockIdx.x;    // 0..127 (A)
    int k = threadIdx.x;   // 0..255 (H)
    Wt[n * HH + k] = (_Float16)W1[k * AA + n];
}

// ---------------------------------------------------------------------------
// K1 (R9 rewrite): barrier-free K-loop.
// - Wt staged to LDS ONCE per block (single __syncthreads in the kernel).
// - A-fragments read DIRECTLY from global X (f32, cvt_pkrtz in reg):
//   each X row belongs to exactly one wave, so no LDS/barrier needed and
//   every byte of X is fetched exactly once, fully pipelined (no vmcnt(0)
//   drains inside the loop -> load stream stays saturated).
// - Wave w owns output rows m0 + w*32 .. +31; acc[4] covers all 128 cols.
// - Epilogue: tanh + W2 dot via in-wave shfl_xor reduction (no LDS, no bar).
// Fragment layouts copied verbatim from the harness-verified kernel.
// ---------------------------------------------------------------------------
__global__ __launch_bounds__(256, 2) void score_mfma(
    const float* __restrict__ X,        // [B*S, H]
    const _Float16* __restrict__ Wt,    // [A, H] f16 (W1 transposed)
    const float* __restrict__ b1,       // [A]
    const float* __restrict__ W2,       // [A]
    const float* __restrict__ b2,       // [1]
    float* __restrict__ scores)         // [B*S]
{
    __shared__ _Float16 Ws2[128 * WST];                  // 67584 B, 2 blocks/CU

    const int tid   = threadIdx.x;
    const int m0    = blockIdx.x * MT;
    const int wid   = tid >> 6;
    const int lane  = tid & 63;
    const int lrow  = lane & 31;
    const int lhalf = lane >> 5;

    // --- stage all of Wt [128][256] f16 into padded LDS, once ---
    #pragma unroll
    for (int p = 0; p < 16; ++p) {
        int idx = tid + p * 256;
        int row = idx >> 5, u = idx & 31;
        *(uint4*)(Ws2 + row * WST + u * 8) =
            *(const uint4*)(Wt + (size_t)row * HH + u * 8);
    }
    __syncthreads();

    floatx16 acc[4];
    #pragma unroll
    for (int nb = 0; nb < 4; ++nb)
        #pragma unroll
        for (int r = 0; r < 16; ++r) acc[nb][r] = 0.0f;

    // A source: this lane's row, k base = lhalf*8
    const float* xrow = X + (size_t)(m0 + wid * 32 + lrow) * HH + lhalf * 8;

    // depth-2 rotating A prefetch; 16 K-steps (k = 16*s), barrier-free
    float4 a0 = *(const float4*)(xrow);
    float4 a1 = *(const float4*)(xrow + 4);
    #pragma unroll
    for (int s = 0; s < 16; ++s) {
        float4 n0 = a0, n1 = a1;
        if (s < 15) {
            n0 = *(const float4*)(xrow + (s + 1) * 16);
            n1 = *(const float4*)(xrow + (s + 1) * 16 + 4);
        }
        union { fp16v2 h2[4]; half8v h8; } ua;
        ua.h2[0] = __builtin_amdgcn_cvt_pkrtz(a0.x, a0.y);
        ua.h2[1] = __builtin_amdgcn_cvt_pkrtz(a0.z, a0.w);
        ua.h2[2] = __builtin_amdgcn_cvt_pkrtz(a1.x, a1.y);
        ua.h2[3] = __builtin_amdgcn_cvt_pkrtz(a1.z, a1.w);
        #pragma unroll
        for (int nb = 0; nb < 4; ++nb) {
            half8v bf = *(half8v*)(Ws2 + (nb * 32 + lrow) * WST + s * 16 + lhalf * 8);
            acc[nb] = __builtin_amdgcn_mfma_f32_32x32x16_f16(ua.h8, bf, acc[nb], 0, 0, 0);
        }
        a0 = n0; a1 = n1;
    }

    // --- epilogue: tanh + dot(W2) with in-wave reduction, no LDS ---
    const float b2v = b2[0];
    float b1v[4], w2v[4];
    #pragma unroll
    for (int nb = 0; nb < 4; ++nb) {
        b1v[nb] = b1[nb * 32 + lrow];
        w2v[nb] = W2[nb * 32 + lrow];
    }
    #pragma unroll
    for (int r = 0; r < 16; ++r) {
        float s = 0.0f;
        #pragma unroll
        for (int nb = 0; nb < 4; ++nb)
            s += fast_tanh(acc[nb][r] + b1v[nb]) * w2v[nb];
        #pragma unroll
        for (int o = 1; o < 32; o <<= 1) s += __shfl_xor(s, o);
        if (lrow == 0) {
            int ridx = (r & 3) + 8 * (r >> 2) + 4 * lhalf;   // C row mapping
            scores[m0 + wid * 32 + ridx] = s + b2v;
        }
    }
}

// ---------------------------------------------------------------------------
// K2 (fused): entmax-1.5 over S per batch row (10 bisect + 4 Newton), then
// support compaction into LDS and the context reduction in the same block.
// ---------------------------------------------------------------------------
__global__ __launch_bounds__(256) void entmax_ctx_kernel(
    const float* __restrict__ X, float* __restrict__ buf, float* __restrict__ ctx)
{
    __shared__ float sred[8];
    __shared__ int   cnt;
    __shared__ int   sidx[SS];    // 16 KB (worst-case full support)
    __shared__ float swt[SS];     // 16 KB

    const int b = blockIdx.x, tid = threadIdx.x;
    const int wid = tid >> 6;
    float* p = buf + (size_t)b * SS;
    const float4* p4 = (const float4*)p;

    if (tid == 0) cnt = 0;

    float z[16];
    #pragma unroll
    for (int jj = 0; jj < 4; ++jj) {
        float4 v = p4[tid * 4 + jj];
        z[jj * 4 + 0] = v.x * 0.5f; z[jj * 4 + 1] = v.y * 0.5f;
        z[jj * 4 + 2] = v.z * 0.5f; z[jj * 4 + 3] = v.w * 0.5f;
    }

    float m = -1e30f;
    #pragma unroll
    for (int j = 0; j < 16; ++j) m = fmaxf(m, z[j]);
    #pragma unroll
    for (int o = 1; o < 64; o <<= 1) m = fmaxf(m, __shfl_xor(m, o));
    if ((tid & 63) == 0) sred[wid] = m;
    __syncthreads();
    m = fmaxf(fmaxf(sred[0], sred[1]), fmaxf(sred[2], sred[3]));
    __syncthreads();
    #pragma unroll
    for (int j = 0; j < 16; ++j) z[j] -= m;

    float lo = -1.0f, hi = 0.0f;
    #pragma unroll 1
    for (int it = 0; it < 10; ++it) {
        float tau = 0.5f * (lo + hi);
        float s0 = 0.f, s1 = 0.f, s2 = 0.f, s3 = 0.f;
        #pragma unroll
        for (int j = 0; j < 16; j += 4) {
            float d0 = fmaxf(z[j]     - tau, 0.0f);
            float d1 = fmaxf(z[j + 1] - tau, 0.0f);
            float d2 = fmaxf(z[j + 2] - tau, 0.0f);
            float d3 = fmaxf(z[j + 3] - tau, 0.0f);
            s0 = fmaf(d0, d0, s0); s1 = fmaf(d1, d1, s1);
            s2 = fmaf(d2, d2, s2); s3 = fmaf(d3, d3, s3);
        }
        float s = (s0 + s1) + (s2 + s3);
        #pragma unroll
        for (int o = 1; o < 64; o <<= 1) s += __shfl_xor(s, o);
        if ((tid & 63) == 0) sred[wid] = s;
        __syncthreads();
        s = (sred[0] + sred[1]) + (sred[2] + sred[3]);
        __syncthreads();
        if (s >= 1.0f) lo = tau; else hi = tau;
    }

    float tau = lo;   // f(lo) >= 1 invariant -> Newton from the left
    #pragma unroll 1
    for (int it = 0; it < 4; ++it) {
        float s0 = 0.f, s1 = 0.f, t0 = 0.f, t1 = 0.f;
        #pragma unroll
        for (int j = 0; j < 16; j += 2) {
            float d0 = fmaxf(z[j]     - tau, 0.0f);
            float d1 = fmaxf(z[j + 1] - tau, 0.0f);
            s0 = fmaf(d0, d0, s0); s1 = fmaf(d1, d1, s1);
            t0 += d0; t1 += d1;
        }
        float s = s0 + s1, t = t0 + t1;
        #pragma unroll
        for (int o = 1; o < 64; o <<= 1) {
            s += __shfl_xor(s, o);
            t += __shfl_xor(t, o);
        }
        if ((tid & 63) == 0) { sred[wid * 2] = s; sred[wid * 2 + 1] = t; }
        __syncthreads();
        s = (sred[0] + sred[2]) + (sred[4] + sred[6]);
        t = (sred[1] + sred[3]) + (sred[5] + sred[7]);
        __syncthreads();
        tau = fminf(tau + (s - 1.0f) / (2.0f * t + 1e-30f), hi);
    }

    // --- weights out (vectorized) + support compaction into LDS ---
    float4* p4w = (float4*)p;
    #pragma unroll
    for (int jj = 0; jj < 4; ++jj) {
        float w[4];
        #pragma unroll
        for (int k = 0; k < 4; ++k) {
            float d = fmaxf(z[jj * 4 + k] - tau, 0.0f);
            w[k] = d * d;
            if (w[k] > 0.0f) {
                int pos = atomicAdd(&cnt, 1);
                sidx[pos] = tid * 16 + jj * 4 + k;
                swt[pos]  = w[k];
            }
        }
        p4w[tid * 4 + jj] = make_float4(w[0], w[1], w[2], w[3]);
    }
    __syncthreads();

    // --- context: ctx[b, tid] = sum over support of w * X[b, s, tid] ---
    const int n = cnt;
    const float* xb = X + (size_t)b * SS * HH + tid;
    float a0 = 0.f, a1 = 0.f, a2 = 0.f, a3 = 0.f;
    int i = 0;
    for (; i + 4 <= n; i += 4) {
        a0 = fmaf(swt[i    ], xb[(size_t)sidx[i    ] * HH], a0);
        a1 = fmaf(swt[i + 1], xb[(size_t)sidx[i + 1] * HH], a1);
        a2 = fmaf(swt[i + 2], xb[(size_t)sidx[i + 2] * HH], a2);
        a3 = fmaf(swt[i + 3], xb[(size_t)sidx[i + 3] * HH], a3);
    }
    for (; i < n; ++i) a0 = fmaf(swt[i], xb[(size_t)sidx[i] * HH], a0);
    ctx[b * HH + tid] = (a0 + a1) + (a2 + a3);
}

extern "C" void kernel_launch(void* const* d_in, const int* in_sizes, int n_in,
                              void* d_out, int out_size, void* d_ws, size_t ws_size,
                              hipStream_t stream) {
    const float* X  = (const float*)d_in[0];
    const float* W1 = (const float*)d_in[1];
    const float* b1 = (const float*)d_in[2];
    const float* W2 = (const float*)d_in[3];
    const float* b2 = (const float*)d_in[4];

    float* out = (float*)d_out;
    float* ctx = out;            // [64*256]
    float* wts = out + BB * HH;  // [64*4096] scores -> weights
    _Float16* Wt = (_Float16*)d_ws;  // [128][256] f16, 64 KB

    convert_w1<<<AA, HH, 0, stream>>>(W1, Wt);
    score_mfma<<<(BB * SS) / MT, 256, 0, stream>>>(X, Wt, b1, W2, b2, wts);
    entmax_ctx_kernel<<<BB, 256, 0, stream>>>(X, wts, ctx);
}

// Round 12
// 390.803 us; speedup vs baseline: 1.0408x; 1.0408x over previous
//
#include <hip/hip_runtime.h>
#include <hip/hip_bf16.h>

#define BB 64
#define SS 4096
#define HH 256
#define AA 128
#define MT 128      // M tile per block (4 waves x 32 rows, acc[4] over col-blocks)
#define BK 64       // K chunk

typedef __fp16 fp16v2 __attribute__((ext_vector_type(2)));   // cvt_pkrtz result type
typedef _Float16 half8v __attribute__((ext_vector_type(8)));
typedef float floatx16 __attribute__((ext_vector_type(16)));

__device__ __forceinline__ float fast_tanh(float x) {
    float xc = fminf(fmaxf(x, -9.0f), 9.0f);
    float e = __expf(2.0f * xc);
    return 1.0f - __fdividef(2.0f, e + 1.0f);
}

// ---------------------------------------------------------------------------
// K0: W1 [H=256][A=128] fp32  ->  Wt [A=128][H=256] f16 (transposed) in d_ws
// ---------------------------------------------------------------------------
__global__ void convert_w1(const float* __restrict__ W1, _Float16* __restrict__ Wt) {
    int n = blockIdx.x;    // 0..127 (A)
    int k = threadIdx.x;   // 0..255 (H)
    Wt[n * HH + k] = (_Float16)W1[k * AA + n];
}

// ---------------------------------------------------------------------------
// K1 (R12): R8 chunked structure + global_load_lds staging.
// - X staged as f32 via global_load_lds (16B widths), LDS linear with
//   source-side XOR swizzle: slot(r,c) = r*16 + (c ^ (r&7))  [16B slots]
//   -> conflict-free ds_read_b128 (8 slot groups x 4 banks = 32 banks).
// - f32->f16 cvt moved to MFMA phase (each element read exactly once).
// - W staged as f16 likewise: slot(r,c) = r*8 + (c ^ (r&7)).
// - LDS 48 KB -> 3 blocks/CU; 2 barriers per chunk (compiler drains vmcnt).
// - Wave w owns rows w*32..+31, acc[4] over 4 col-blocks (R11-verified
//   layout); shuffle epilogue (R11-verified C-row mapping).
// ---------------------------------------------------------------------------
__global__ __launch_bounds__(256, 3) void score_mfma(
    const float* __restrict__ X,        // [B*S, H]
    const _Float16* __restrict__ Wt,    // [A, H] f16 (W1 transposed)
    const float* __restrict__ b1,       // [A]
    const float* __restrict__ W2,       // [A]
    const float* __restrict__ b2,       // [1]
    float* __restrict__ scores)         // [B*S]
{
    __shared__ __align__(16) char smem[49152];           // 48 KB
    float*    Xs = (float*)smem;                         // 32 KB: 2048 16B slots
    _Float16* Ws = (_Float16*)(smem + 32768);            // 16 KB: 1024 16B slots

    const int tid   = threadIdx.x;
    const int m0    = blockIdx.x * MT;
    const int wid   = tid >> 6;
    const int lane  = tid & 63;
    const int lrow  = lane & 31;
    const int lhalf = lane >> 5;

    floatx16 acc[4];
    #pragma unroll
    for (int nb = 0; nb < 4; ++nb)
        #pragma unroll
        for (int r = 0; r < 16; ++r) acc[nb][r] = 0.0f;

    const int rl  = wid * 32 + lrow;   // this lane's A row (0..127)
    const int swz = rl & 7;

    for (int k0 = 0; k0 < HH; k0 += BK) {
        // --- stage X chunk [128 rows][64 f32] via global_load_lds ---
        // slot S = (p*4+wid)*64 + lane; dest = lds_base + S*16 (HW: base+lane*16)
        #pragma unroll
        for (int p = 0; p < 8; ++p) {
            int S = (p * 4 + wid) * 64 + lane;
            int r = S >> 4;
            int c = (S & 15) ^ (r & 7);            // pre-swizzled source col
            const float* gp = X + (size_t)(m0 + r) * HH + k0 + c * 4;
            __builtin_amdgcn_global_load_lds(
                (const __attribute__((address_space(1))) void*)gp,
                (__attribute__((address_space(3))) void*)(smem + (p * 4 + wid) * 1024),
                16, 0, 0);
        }
        // --- stage W chunk [128 rows][64 f16] via global_load_lds ---
        #pragma unroll
        for (int p = 0; p < 4; ++p) {
            int S = (p * 4 + wid) * 64 + lane;
            int r = S >> 3;
            int c = (S & 7) ^ (r & 7);
            const _Float16* gp = Wt + (size_t)r * HH + k0 + c * 8;
            __builtin_amdgcn_global_load_lds(
                (const __attribute__((address_space(1))) void*)gp,
                (__attribute__((address_space(3))) void*)(smem + 32768 + (p * 4 + wid) * 1024),
                16, 0, 0);
        }
        __syncthreads();   // compiler emits vmcnt(0) drain -> LDS valid

        // --- MFMA phase: cvt-on-read A (f32->f16), swizzled ds_reads ---
        #pragma unroll
        for (int s = 0; s < 4; ++s) {
            int c0 = s * 4 + lhalf * 2;            // 16B col of k = s*16 + lhalf*8
            float4 xa = *(float4*)(Xs + (size_t)(rl * 16 + ((c0    ) ^ swz)) * 4);
            float4 xb = *(float4*)(Xs + (size_t)(rl * 16 + ((c0 + 1) ^ swz)) * 4);
            union { fp16v2 h2[4]; half8v h8; } ua;
            ua.h2[0] = __builtin_amdgcn_cvt_pkrtz(xa.x, xa.y);
            ua.h2[1] = __builtin_amdgcn_cvt_pkrtz(xa.z, xa.w);
            ua.h2[2] = __builtin_amdgcn_cvt_pkrtz(xb.x, xb.y);
            ua.h2[3] = __builtin_amdgcn_cvt_pkrtz(xb.z, xb.w);
            #pragma unroll
            for (int nb = 0; nb < 4; ++nb) {
                int rb = nb * 32 + lrow;
                int cb = (s * 2 + lhalf) ^ (rb & 7);
                half8v bf = *(half8v*)(Ws + (size_t)(rb * 8 + cb) * 8);
                acc[nb] = __builtin_amdgcn_mfma_f32_32x32x16_f16(ua.h8, bf, acc[nb], 0, 0, 0);
            }
        }
        __syncthreads();   // all waves done reading before next-stage overwrite
    }

    // --- epilogue: tanh + dot(W2), in-wave shfl reduction (R11-verified) ---
    const float b2v = b2[0];
    float b1v[4], w2v[4];
    #pragma unroll
    for (int nb = 0; nb < 4; ++nb) {
        b1v[nb] = b1[nb * 32 + lrow];
        w2v[nb] = W2[nb * 32 + lrow];
    }
    #pragma unroll
    for (int r = 0; r < 16; ++r) {
        float s = 0.0f;
        #pragma unroll
        for (int nb = 0; nb < 4; ++nb)
            s += fast_tanh(acc[nb][r] + b1v[nb]) * w2v[nb];
        #pragma unroll
        for (int o = 1; o < 32; o <<= 1) s += __shfl_xor(s, o);
        if (lrow == 0) {
            int ridx = (r & 3) + 8 * (r >> 2) + 4 * lhalf;   // C row mapping
            scores[m0 + wid * 32 + ridx] = s + b2v;
        }
    }
}

// ---------------------------------------------------------------------------
// K2 (fused): entmax-1.5 over S per batch row (10 bisect + 4 Newton), then
// support compaction into LDS and the context reduction in the same block.
// ---------------------------------------------------------------------------
__global__ __launch_bounds__(256) void entmax_ctx_kernel(
    const float* __restrict__ X, float* __restrict__ buf, float* __restrict__ ctx)
{
    __shared__ float sred[8];
    __shared__ int   cnt;
    __shared__ int   sidx[SS];    // 16 KB (worst-case full support)
    __shared__ float swt[SS];     // 16 KB

    const int b = blockIdx.x, tid = threadIdx.x;
    const int wid = tid >> 6;
    float* p = buf + (size_t)b * SS;
    const float4* p4 = (const float4*)p;

    if (tid == 0) cnt = 0;

    float z[16];
    #pragma unroll
    for (int jj = 0; jj < 4; ++jj) {
        float4 v = p4[tid * 4 + jj];
        z[jj * 4 + 0] = v.x * 0.5f; z[jj * 4 + 1] = v.y * 0.5f;
        z[jj * 4 + 2] = v.z * 0.5f; z[jj * 4 + 3] = v.w * 0.5f;
    }

    float m = -1e30f;
    #pragma unroll
    for (int j = 0; j < 16; ++j) m = fmaxf(m, z[j]);
    #pragma unroll
    for (int o = 1; o < 64; o <<= 1) m = fmaxf(m, __shfl_xor(m, o));
    if ((tid & 63) == 0) sred[wid] = m;
    __syncthreads();
    m = fmaxf(fmaxf(sred[0], sred[1]), fmaxf(sred[2], sred[3]));
    __syncthreads();
    #pragma unroll
    for (int j = 0; j < 16; ++j) z[j] -= m;

    float lo = -1.0f, hi = 0.0f;
    #pragma unroll 1
    for (int it = 0; it < 10; ++it) {
        float tau = 0.5f * (lo + hi);
        float s0 = 0.f, s1 = 0.f, s2 = 0.f, s3 = 0.f;
        #pragma unroll
        for (int j = 0; j < 16; j += 4) {
            float d0 = fmaxf(z[j]     - tau, 0.0f);
            float d1 = fmaxf(z[j + 1] - tau, 0.0f);
            float d2 = fmaxf(z[j + 2] - tau, 0.0f);
            float d3 = fmaxf(z[j + 3] - tau, 0.0f);
            s0 = fmaf(d0, d0, s0); s1 = fmaf(d1, d1, s1);
            s2 = fmaf(d2, d2, s2); s3 = fmaf(d3, d3, s3);
        }
        float s = (s0 + s1) + (s2 + s3);
        #pragma unroll
        for (int o = 1; o < 64; o <<= 1) s += __shfl_xor(s, o);
        if ((tid & 63) == 0) sred[wid] = s;
        __syncthreads();
        s = (sred[0] + sred[1]) + (sred[2] + sred[3]);
        __syncthreads();
        if (s >= 1.0f) lo = tau; else hi = tau;
    }

    float tau = lo;   // f(lo) >= 1 invariant -> Newton from the left
    #pragma unroll 1
    for (int it = 0; it < 4; ++it) {
        float s0 = 0.f, s1 = 0.f, t0 = 0.f, t1 = 0.f;
        #pragma unroll
        for (int j = 0; j < 16; j += 2) {
            float d0 = fmaxf(z[j]     - tau, 0.0f);
            float d1 = fmaxf(z[j + 1] - tau, 0.0f);
            s0 = fmaf(d0, d0, s0); s1 = fmaf(d1, d1, s1);
            t0 += d0; t1 += d1;
        }
        float s = s0 + s1, t = t0 + t1;
        #pragma unroll
        for (int o = 1; o < 64; o <<= 1) {
            s += __shfl_xor(s, o);
            t += __shfl_xor(t, o);
        }
        if ((tid & 63) == 0) { sred[wid * 2] = s; sred[wid * 2 + 1] = t; }
        __syncthreads();
        s = (sred[0] + sred[2]) + (sred[4] + sred[6]);
        t = (sred[1] + sred[3]) + (sred[5] + sred[7]);
        __syncthreads();
        tau = fminf(tau + (s - 1.0f) / (2.0f * t + 1e-30f), hi);
    }

    // --- weights out (vectorized) + support compaction into LDS ---
    float4* p4w = (float4*)p;
    #pragma unroll
    for (int jj = 0; jj < 4; ++jj) {
        float w[4];
        #pragma unroll
        for (int k = 0; k < 4; ++k) {
            float d = fmaxf(z[jj * 4 + k] - tau, 0.0f);
            w[k] = d * d;
            if (w[k] > 0.0f) {
                int pos = atomicAdd(&cnt, 1);
                sidx[pos] = tid * 16 + jj * 4 + k;
                swt[pos]  = w[k];
            }
        }
        p4w[tid * 4 + jj] = make_float4(w[0], w[1], w[2], w[3]);
    }
    __syncthreads();

    // --- context: ctx[b, tid] = sum over support of w * X[b, s, tid] ---
    const int n = cnt;
    const float* xb = X + (size_t)b * SS * HH + tid;
    float a0 = 0.f, a1 = 0.f, a2 = 0.f, a3 = 0.f;
    int i = 0;
    for (; i + 4 <= n; i += 4) {
        a0 = fmaf(swt[i    ], xb[(size_t)sidx[i    ] * HH], a0);
        a1 = fmaf(swt[i + 1], xb[(size_t)sidx[i + 1] * HH], a1);
        a2 = fmaf(swt[i + 2], xb[(size_t)sidx[i + 2] * HH], a2);
        a3 = fmaf(swt[i + 3], xb[(size_t)sidx[i + 3] * HH], a3);
    }
    for (; i < n; ++i) a0 = fmaf(swt[i], xb[(size_t)sidx[i] * HH], a0);
    ctx[b * HH + tid] = (a0 + a1) + (a2 + a3);
}

extern "C" void kernel_launch(void* const* d_in, const int* in_sizes, int n_in,
                              void* d_out, int out_size, void* d_ws, size_t ws_size,
                              hipStream_t stream) {
    const float* X  = (const float*)d_in[0];
    const float* W1 = (const float*)d_in[1];
    const float* b1 = (const float*)d_in[2];
    const float* W2 = (const float*)d_in[3];
    const float* b2 = (const float*)d_in[4];

    float* out = (float*)d_out;
    float* ctx = out;            // [64*256]
    float* wts = out + BB * HH;  // [64*4096] scores -> weights
    _Float16* Wt = (_Float16*)d_ws;  // [128][256] f16, 64 KB

    convert_w1<<<AA, HH, 0, stream>>>(W1, Wt);
    score_mfma<<<(BB * SS) / MT, 256, 0, stream>>>(X, Wt, b1, W2, b2, wts);
    entmax_ctx_kernel<<<BB, 256, 0, stream>>>(X, wts, ctx);
}